// Round 3
// baseline (3760.842 us; speedup 1.0000x reference)
//
#include <hip/hip_runtime.h>
#include <hip/hip_bf16.h>

// Problem constants: B=4, N=2048, DIM=512, H=8, DH=64, ORDER=3, TOPK=64, INNER=512
#define SLOTS 80   // sparse slots per row (64 + tie headroom)

// ---------------------------------------------------------------------------
// K1/K4: fp32 tiled GEMM with bias: C = A(MxK) @ B(KxN) + bias(N)
// BM=BN=128, BK=16, 256 threads, 8x8 per thread. (unchanged from R2)
// ---------------------------------------------------------------------------
__global__ __launch_bounds__(256)
void sgemm_bias(const float* __restrict__ A, const float* __restrict__ Bm,
                const float* __restrict__ bias, float* __restrict__ C,
                int M, int N, int K)
{
    __shared__ float As[16][132];
    __shared__ float Bs[16][132];

    const int t  = threadIdx.x;
    const int tx = t & 15, ty = t >> 4;
    const int bm = blockIdx.y << 7, bn = blockIdx.x << 7;

    const int arow = t >> 2,  ak4 = (t & 3) << 2;
    const int bkr  = t >> 5,  bc4 = (t & 31) << 2;

    float4 pa[2], pb[2];
#pragma unroll
    for (int s = 0; s < 2; ++s) {
        pa[s] = *(const float4*)&A[(size_t)(bm + arow + (s << 6)) * K + ak4];
        pb[s] = *(const float4*)&Bm[(size_t)(bkr + (s << 3)) * N + bn + bc4];
    }

    float acc[8][8] = {};

    for (int k0 = 0; k0 < K; k0 += 16) {
        __syncthreads();
#pragma unroll
        for (int s = 0; s < 2; ++s) {
            const int ar = arow + (s << 6);
            As[ak4 + 0][ar] = pa[s].x;
            As[ak4 + 1][ar] = pa[s].y;
            As[ak4 + 2][ar] = pa[s].z;
            As[ak4 + 3][ar] = pa[s].w;
            *(float4*)&Bs[bkr + (s << 3)][bc4] = pb[s];
        }
        __syncthreads();
        if (k0 + 16 < K) {
#pragma unroll
            for (int s = 0; s < 2; ++s) {
                pa[s] = *(const float4*)&A[(size_t)(bm + arow + (s << 6)) * K + k0 + 16 + ak4];
                pb[s] = *(const float4*)&Bm[(size_t)(k0 + 16 + bkr + (s << 3)) * N + bn + bc4];
            }
        }
#pragma unroll
        for (int kk = 0; kk < 16; ++kk) {
            float4 a0 = *(const float4*)&As[kk][(ty << 3) + 0];
            float4 a1 = *(const float4*)&As[kk][(ty << 3) + 4];
            float4 b0 = *(const float4*)&Bs[kk][(tx << 2)];
            float4 b1 = *(const float4*)&Bs[kk][64 + (tx << 2)];
            float ar[8] = {a0.x, a0.y, a0.z, a0.w, a1.x, a1.y, a1.z, a1.w};
            float br[8] = {b0.x, b0.y, b0.z, b0.w, b1.x, b1.y, b1.z, b1.w};
#pragma unroll
            for (int i = 0; i < 8; ++i)
#pragma unroll
                for (int j = 0; j < 8; ++j)
                    acc[i][j] = fmaf(ar[i], br[j], acc[i][j]);
        }
    }

    float bb[8];
#pragma unroll
    for (int j = 0; j < 4; ++j) {
        bb[j]     = bias[bn + (tx << 2) + j];
        bb[j + 4] = bias[bn + 64 + (tx << 2) + j];
    }
#pragma unroll
    for (int i = 0; i < 8; ++i) {
        const size_t row = (size_t)(bm + (ty << 3) + i);
        float4 o0 = {acc[i][0] + bb[0], acc[i][1] + bb[1], acc[i][2] + bb[2], acc[i][3] + bb[3]};
        float4 o1 = {acc[i][4] + bb[4], acc[i][5] + bb[5], acc[i][6] + bb[6], acc[i][7] + bb[7]};
        *(float4*)&C[row * N + bn + (tx << 2)]      = o0;
        *(float4*)&C[row * N + bn + 64 + (tx << 2)] = o1;
    }
}

// ---------------------------------------------------------------------------
// K2 v3: row-stationary scores + fused exact top-k.
// Block = 4 waves; wave owns 6 rows; lane owns 32 cols (acc[6][32] in VGPRs).
// K streamed through double-buffered LDS tiles (128 cols x 64 d, swizzled),
// q via wave-uniform scalar loads (SGPR FMA operands). No score matrix in
// LDS or global. Per-score fmaf chain: d ascending 0..63 (bit-identical R2).
// LDS = 64 KB -> 2 blocks/CU.
// ---------------------------------------------------------------------------
__global__ __launch_bounds__(256, 2)
void scores_topk(const float* __restrict__ qkv, float* __restrict__ svals,
                 unsigned short* __restrict__ sidx, int* __restrict__ scnt)
{
    __shared__ float kt[16384];   // 2 x (128 cols x 64 d), 16B-slot swizzled

    const int t    = threadIdx.x;
    const int lane = t & 63;
    const int wid  = t >> 6;
    const int bh   = blockIdx.y;
    const int b    = bh >> 3, h = bh & 7;
    const size_t rowbase = (size_t)b * 2048;
    const int qoff = h << 6;
    const int koff = 512 + (h << 6);
    const int swz  = lane & 7;

    // wave's 6 rows (uniform): block covers 24 rows
    int wr0 = blockIdx.x * 24 + wid * 6;
    wr0 = __builtin_amdgcn_readfirstlane(wr0);
    const float* qb[6];
#pragma unroll
    for (int r = 0; r < 6; ++r)
        qb[r] = qkv + (rowbase + (size_t)(wr0 + r)) * 1536 + qoff;

    // staging maps: thread t stages 8 float4s: col c=(t>>4)+16i, slot sl=t&15
    const int sl = t & 15;
    float4 pre[8];

    auto stage_load = [&](int tn) {
#pragma unroll
        for (int i = 0; i < 8; ++i) {
            const int c = (t >> 4) + (i << 4);
            pre[i] = *(const float4*)
                &qkv[(rowbase + (size_t)((tn << 7) + c)) * 1536 + koff + (sl << 2)];
        }
    };
    auto stage_write = [&](int bufi) {
#pragma unroll
        for (int i = 0; i < 8; ++i) {
            const int c = (t >> 4) + (i << 4);
            *(float4*)&kt[(bufi << 13) + (c << 6) + ((sl ^ (c & 7)) << 2)] = pre[i];
        }
    };

    stage_load(0);
    stage_write(0);          // compiler inserts vmcnt wait
    stage_load(1);
    __syncthreads();         // buf0 ready

    float acc[6][32] = {};

#pragma unroll
    for (int tt = 0; tt < 16; ++tt) {
        const int cur = tt & 1;
        const int cb  = cur << 13;
#pragma unroll
        for (int s = 0; s < 16; ++s) {
            const float4 ka = *(const float4*)&kt[cb + (lane << 6) + ((s ^ swz) << 2)];
            const float4 kb = *(const float4*)&kt[cb + 4096 + (lane << 6) + ((s ^ swz) << 2)];
#pragma unroll
            for (int r = 0; r < 6; ++r) {
                const float4 q4 = *(const float4*)&qb[r][s << 2];   // uniform -> s_load
                float a = acc[r][2 * tt];
                a = fmaf(q4.x, ka.x, a); a = fmaf(q4.y, ka.y, a);
                a = fmaf(q4.z, ka.z, a); a = fmaf(q4.w, ka.w, a);
                acc[r][2 * tt] = a;
                float c2 = acc[r][2 * tt + 1];
                c2 = fmaf(q4.x, kb.x, c2); c2 = fmaf(q4.y, kb.y, c2);
                c2 = fmaf(q4.z, kb.z, c2); c2 = fmaf(q4.w, kb.w, c2);
                acc[r][2 * tt + 1] = c2;
            }
        }
        if (tt < 15) {
            stage_write(1 - cur);                // tile tt+1 (loads hidden under compute)
            if (tt < 14) stage_load(tt + 2);     // issue next loads early
            __syncthreads();                     // buf[1-cur] ready
        }
    }

    // phase B: per wave, 6 rows; exact 64th-largest via bit bisection on acc
#pragma unroll
    for (int rq = 0; rq < 6; ++rq) {
        const int rglob = wr0 + rq;
        if (rglob >= 2048) continue;             // ragged tail (uniform branch)

        float    fv[32];
        unsigned uv[32];
#pragma unroll
        for (int m = 0; m < 32; ++m) {
            const float x = acc[rq][m] * 0.125f;
            fv[m] = x;
            const unsigned bx = __float_as_uint(x);
            uv[m] = bx ^ (unsigned)(((int)bx >> 31) | 0x80000000);
        }
        unsigned lo = 0;
#pragma unroll 1
        for (int bit = 31; bit >= 0; --bit) {
            const unsigned mid = lo | (1u << bit);
            int c = 0;
#pragma unroll
            for (int m = 0; m < 32; ++m) {
                unsigned long long ball = __ballot(uv[m] >= mid);
                c += __popcll(ball);
            }
            if (c >= 64) lo = mid;   // uniform (ballot count is wave-uniform)
        }
        unsigned um = 0;
#pragma unroll
        for (int m = 0; m < 32; ++m) um = uv[m] > um ? uv[m] : um;
#pragma unroll
        for (int off = 1; off < 64; off <<= 1) {
            const unsigned o = (unsigned)__shfl_xor((int)um, off, 64);
            um = o > um ? o : um;
        }
        const unsigned mb = (um & 0x80000000u) ? (um ^ 0x80000000u) : ~um;
        const float Mx = __uint_as_float(mb);

        float zs = 0.f;
#pragma unroll
        for (int m = 0; m < 32; ++m) {
            const bool keep = uv[m] >= lo;
            const float ex = keep ? __expf(fv[m] - Mx) : 0.f;
            fv[m] = ex;
            zs += ex;
        }
#pragma unroll
        for (int off = 1; off < 64; off <<= 1) zs += __shfl_xor(zs, off, 64);
        const float zinv = 1.0f / zs;

        const size_t grow = (size_t)bh * 2048 + rglob;
        float* vd          = svals + grow * SLOTS;
        unsigned short* id = sidx  + grow * SLOTS;
        const unsigned long long pre64 = (1ull << lane) - 1ull;
        int base = 0;
#pragma unroll 1
        for (int m = 0; m < 32; ++m) {
            const bool keep = uv[m] >= lo;
            unsigned long long ball = __ballot(keep);
            if (keep) {
                const int my = base + __popcll(ball & pre64);
                if (my < SLOTS) {
                    vd[my] = fv[m] * zinv;
                    id[my] = (unsigned short)(((m >> 1) << 7) + ((m & 1) << 6) + lane);
                }
            }
            base += __popcll(ball);
        }
        if (lane == 0) scnt[grow] = base < SLOTS ? base : SLOTS;
    }
}

// ---------------------------------------------------------------------------
// K3: sparse attn application (unchanged).
// ---------------------------------------------------------------------------
__global__ __launch_bounds__(256)
void spmm(const float* __restrict__ svals, const unsigned short* __restrict__ sidx,
          const int* __restrict__ scnt, const float* __restrict__ qkv,
          const float* __restrict__ vin, float* __restrict__ vout,
          float* __restrict__ res, const float* __restrict__ alphas_raw, int order)
{
    const int lane = threadIdx.x & 63;
    const int gr   = (blockIdx.x << 2) + (threadIdx.x >> 6);  // 0..65535
    const int bh   = gr >> 11, n = gr & 2047;
    const int b    = bh >> 3,  h = bh & 7;

    const float* vb;
    int stride;
    if (order == 0) { vb = qkv + (size_t)b * 2048 * 1536 + 1024 + (h << 6); stride = 1536; }
    else            { vb = vin + ((size_t)bh << 17);                        stride = 64;   }

    const int cnt = scnt[gr];
    const float* va          = svals + (size_t)gr * SLOTS;
    const unsigned short* ia = sidx  + (size_t)gr * SLOTS;

    float acc = 0.f;
    int j = 0;
    for (; j + 4 <= cnt; j += 4) {
        float a0 = va[j], a1 = va[j + 1], a2 = va[j + 2], a3 = va[j + 3];
        int   i0 = ia[j], i1 = ia[j + 1], i2 = ia[j + 2], i3 = ia[j + 3];
        acc += a0 * vb[(size_t)i0 * stride + lane];
        acc += a1 * vb[(size_t)i1 * stride + lane];
        acc += a2 * vb[(size_t)i2 * stride + lane];
        acc += a3 * vb[(size_t)i3 * stride + lane];
    }
    for (; j < cnt; ++j) acc += va[j] * vb[(size_t)ia[j] * stride + lane];

    if (order < 2) vout[((size_t)gr << 6) + lane] = acc;

    float ar    = alphas_raw[(order << 3) + h];
    float alpha = ar * 0.5f * (1.0f + erff(ar * 0.70710678f));  // exact gelu
    size_t ro = ((size_t)b * 2048 + n) * 512 + (h << 6) + lane;
    float av  = alpha * acc;
    if (order == 0) res[ro] = av;
    else            res[ro] += av;
}

// ---------------------------------------------------------------------------
extern "C" void kernel_launch(void* const* d_in, const int* in_sizes, int n_in,
                              void* d_out, int out_size, void* d_ws, size_t ws_size,
                              hipStream_t stream)
{
    const float* x      = (const float*)d_in[0];
    const float* Wqkv   = (const float*)d_in[1];
    const float* bqkv   = (const float*)d_in[2];
    const float* Wout   = (const float*)d_in[3];
    const float* bout   = (const float*)d_in[4];
    const float* alphas = (const float*)d_in[5];
    float* out = (float*)d_out;

    // workspace layout (bytes)
    char* ws = (char*)d_ws;
    float*          qkvb  = (float*)ws;                       // 8192*1536*4 = 50331648
    float*          svals = (float*)(ws + 50331648);          // 65536*80*4  = 20971520
    unsigned short* sidxp = (unsigned short*)(ws + 71303168); // 65536*80*2  = 10485760
    int*            scntp = (int*)(ws + 81788928);            // 65536*4     = 262144
    float*          v1    = (float*)(ws + 82051072);          // 16777216
    float*          v2    = (float*)(ws + 98828288);          // 16777216
    float*          resb  = (float*)(ws + 115605504);         // 16777216
    if (ws_size < 132382720) return;                          // need ~126 MB

    // K1: qkv = x @ Wqkv + bqkv
    sgemm_bias<<<dim3(1536 / 128, 8192 / 128), 256, 0, stream>>>(
        x, Wqkv, bqkv, qkvb, 8192, 1536, 512);

    // K2: scores (in regs) -> exact top-64(+ties) -> softmax -> sparse rows
    // 86 row-blocks x 24 rows = 2064 (ragged tail guarded)
    scores_topk<<<dim3(86, 32), 256, 0, stream>>>(qkvb, svals, sidxp, scntp);

    // K3 x3: polynomial filter (sparse A applications)
    spmm<<<16384, 256, 0, stream>>>(svals, sidxp, scntp, qkvb, nullptr, v1, resb, alphas, 0);
    spmm<<<16384, 256, 0, stream>>>(svals, sidxp, scntp, qkvb, v1, v2, resb, alphas, 1);
    spmm<<<16384, 256, 0, stream>>>(svals, sidxp, scntp, qkvb, v2, nullptr, resb, alphas, 2);

    // K4: out = res @ Wout + bout
    sgemm_bias<<<dim3(512 / 128, 8192 / 128), 256, 0, stream>>>(
        resb, Wout, bout, out, 8192, 512, 512);
}

// Round 4
// 3437.824 us; speedup vs baseline: 1.0940x; 1.0940x over previous
//
#include <hip/hip_runtime.h>
#include <hip/hip_bf16.h>

// Problem constants: B=4, N=2048, DIM=512, H=8, DH=64, ORDER=3, TOPK=64, INNER=512
#define SLOTS 80   // sparse slots per row (64 + tie headroom)

// ---------------------------------------------------------------------------
// K1/K4: fp32 tiled GEMM with bias: C = A(MxK) @ B(KxN) + bias(N)
// BM=BN=128, BK=16, 256 threads, 8x8 per thread. (unchanged)
// ---------------------------------------------------------------------------
__global__ __launch_bounds__(256)
void sgemm_bias(const float* __restrict__ A, const float* __restrict__ Bm,
                const float* __restrict__ bias, float* __restrict__ C,
                int M, int N, int K)
{
    __shared__ float As[16][132];
    __shared__ float Bs[16][132];

    const int t  = threadIdx.x;
    const int tx = t & 15, ty = t >> 4;
    const int bm = blockIdx.y << 7, bn = blockIdx.x << 7;

    const int arow = t >> 2,  ak4 = (t & 3) << 2;
    const int bkr  = t >> 5,  bc4 = (t & 31) << 2;

    float4 pa[2], pb[2];
#pragma unroll
    for (int s = 0; s < 2; ++s) {
        pa[s] = *(const float4*)&A[(size_t)(bm + arow + (s << 6)) * K + ak4];
        pb[s] = *(const float4*)&Bm[(size_t)(bkr + (s << 3)) * N + bn + bc4];
    }

    float acc[8][8] = {};

    for (int k0 = 0; k0 < K; k0 += 16) {
        __syncthreads();
#pragma unroll
        for (int s = 0; s < 2; ++s) {
            const int ar = arow + (s << 6);
            As[ak4 + 0][ar] = pa[s].x;
            As[ak4 + 1][ar] = pa[s].y;
            As[ak4 + 2][ar] = pa[s].z;
            As[ak4 + 3][ar] = pa[s].w;
            *(float4*)&Bs[bkr + (s << 3)][bc4] = pb[s];
        }
        __syncthreads();
        if (k0 + 16 < K) {
#pragma unroll
            for (int s = 0; s < 2; ++s) {
                pa[s] = *(const float4*)&A[(size_t)(bm + arow + (s << 6)) * K + k0 + 16 + ak4];
                pb[s] = *(const float4*)&Bm[(size_t)(k0 + 16 + bkr + (s << 3)) * N + bn + bc4];
            }
        }
#pragma unroll
        for (int kk = 0; kk < 16; ++kk) {
            float4 a0 = *(const float4*)&As[kk][(ty << 3) + 0];
            float4 a1 = *(const float4*)&As[kk][(ty << 3) + 4];
            float4 b0 = *(const float4*)&Bs[kk][(tx << 2)];
            float4 b1 = *(const float4*)&Bs[kk][64 + (tx << 2)];
            float ar[8] = {a0.x, a0.y, a0.z, a0.w, a1.x, a1.y, a1.z, a1.w};
            float br[8] = {b0.x, b0.y, b0.z, b0.w, b1.x, b1.y, b1.z, b1.w};
#pragma unroll
            for (int i = 0; i < 8; ++i)
#pragma unroll
                for (int j = 0; j < 8; ++j)
                    acc[i][j] = fmaf(ar[i], br[j], acc[i][j]);
        }
    }

    float bb[8];
#pragma unroll
    for (int j = 0; j < 4; ++j) {
        bb[j]     = bias[bn + (tx << 2) + j];
        bb[j + 4] = bias[bn + 64 + (tx << 2) + j];
    }
#pragma unroll
    for (int i = 0; i < 8; ++i) {
        const size_t row = (size_t)(bm + (ty << 3) + i);
        float4 o0 = {acc[i][0] + bb[0], acc[i][1] + bb[1], acc[i][2] + bb[2], acc[i][3] + bb[3]};
        float4 o1 = {acc[i][4] + bb[4], acc[i][5] + bb[5], acc[i][6] + bb[6], acc[i][7] + bb[7]};
        *(float4*)&C[row * N + bn + (tx << 2)]      = o0;
        *(float4*)&C[row * N + bn + 64 + (tx << 2)] = o1;
    }
}

// ---------------------------------------------------------------------------
// K2 v4: row-stationary scores + fused exact top-k, MACRO-UNROLLED k-tiles.
// Block = 4 waves; wave owns 4 rows; lane owns 32 cols (acc[4][32], all
// indices compile-time literals -> guaranteed VGPR allocation, no scratch).
// K streamed through double-buffered LDS tiles (128 cols x 64 d, swizzled),
// q via wave-uniform scalar loads. Per-score fmaf chain: d ascending 0..63.
// LDS = 64 KB -> 2 blocks/CU.
// ---------------------------------------------------------------------------
__global__ __launch_bounds__(256, 2)
void scores_topk(const float* __restrict__ qkv, float* __restrict__ svals,
                 unsigned short* __restrict__ sidx, int* __restrict__ scnt)
{
    __shared__ float kt[16384];   // 2 x (128 cols x 64 d), 16B-slot swizzled

    const int t    = threadIdx.x;
    const int lane = t & 63;
    const int wid  = t >> 6;
    const int bh   = blockIdx.y;
    const int b    = bh >> 3, h = bh & 7;
    const size_t rowbase = (size_t)b * 2048;
    const int qoff = h << 6;
    const int koff = 512 + (h << 6);
    const int swz  = lane & 7;

    // wave's 4 rows (uniform): block covers 16 rows
    int wr0 = (blockIdx.x << 4) + (wid << 2);
    wr0 = __builtin_amdgcn_readfirstlane(wr0);
    const float* qb0 = qkv + (rowbase + (size_t)(wr0 + 0)) * 1536 + qoff;
    const float* qb1 = qkv + (rowbase + (size_t)(wr0 + 1)) * 1536 + qoff;
    const float* qb2 = qkv + (rowbase + (size_t)(wr0 + 2)) * 1536 + qoff;
    const float* qb3 = qkv + (rowbase + (size_t)(wr0 + 3)) * 1536 + qoff;

    // staging maps: thread t stages 8 float4s: col c=(t>>4)+16i, slot sl=t&15
    const int sl = t & 15;
    float4 pre[8];

    auto stage_load = [&](int tn) {
#pragma unroll
        for (int i = 0; i < 8; ++i) {
            const int c = (t >> 4) + (i << 4);
            pre[i] = *(const float4*)
                &qkv[(rowbase + (size_t)((tn << 7) + c)) * 1536 + koff + (sl << 2)];
        }
    };
    auto stage_write = [&](int bufi) {
#pragma unroll
        for (int i = 0; i < 8; ++i) {
            const int c = (t >> 4) + (i << 4);
            *(float4*)&kt[(bufi << 13) + (c << 6) + ((sl ^ (c & 7)) << 2)] = pre[i];
        }
    };

    stage_load(0);
    stage_write(0);          // compiler inserts vmcnt wait
    stage_load(1);
    __syncthreads();         // buf0 ready

    float acc[4][32];
#pragma unroll
    for (int r = 0; r < 4; ++r)
#pragma unroll
        for (int m = 0; m < 32; ++m) acc[r][m] = 0.f;

    // One k-tile: 128 cols x 64 d. Lane's two cols: lane, lane+64.
    // All acc indices are literals (TT is a macro literal).
#define STEP(TT)                                                               \
    {                                                                          \
        const int cb = ((TT) & 1) << 13;                                       \
        _Pragma("unroll")                                                      \
        for (int s = 0; s < 16; ++s) {                                         \
            const float4 ka = *(const float4*)&kt[cb + (lane << 6) + ((s ^ swz) << 2)];          \
            const float4 kb = *(const float4*)&kt[cb + 4096 + (lane << 6) + ((s ^ swz) << 2)];   \
            float4 q4;                                                         \
            float a, c2;                                                       \
            q4 = *(const float4*)&qb0[s << 2];                                 \
            a = acc[0][2 * (TT)];                                              \
            a = fmaf(q4.x, ka.x, a); a = fmaf(q4.y, ka.y, a);                  \
            a = fmaf(q4.z, ka.z, a); a = fmaf(q4.w, ka.w, a);                  \
            acc[0][2 * (TT)] = a;                                              \
            c2 = acc[0][2 * (TT) + 1];                                         \
            c2 = fmaf(q4.x, kb.x, c2); c2 = fmaf(q4.y, kb.y, c2);              \
            c2 = fmaf(q4.z, kb.z, c2); c2 = fmaf(q4.w, kb.w, c2);              \
            acc[0][2 * (TT) + 1] = c2;                                         \
            q4 = *(const float4*)&qb1[s << 2];                                 \
            a = acc[1][2 * (TT)];                                              \
            a = fmaf(q4.x, ka.x, a); a = fmaf(q4.y, ka.y, a);                  \
            a = fmaf(q4.z, ka.z, a); a = fmaf(q4.w, ka.w, a);                  \
            acc[1][2 * (TT)] = a;                                              \
            c2 = acc[1][2 * (TT) + 1];                                         \
            c2 = fmaf(q4.x, kb.x, c2); c2 = fmaf(q4.y, kb.y, c2);              \
            c2 = fmaf(q4.z, kb.z, c2); c2 = fmaf(q4.w, kb.w, c2);              \
            acc[1][2 * (TT) + 1] = c2;                                         \
            q4 = *(const float4*)&qb2[s << 2];                                 \
            a = acc[2][2 * (TT)];                                              \
            a = fmaf(q4.x, ka.x, a); a = fmaf(q4.y, ka.y, a);                  \
            a = fmaf(q4.z, ka.z, a); a = fmaf(q4.w, ka.w, a);                  \
            acc[2][2 * (TT)] = a;                                              \
            c2 = acc[2][2 * (TT) + 1];                                         \
            c2 = fmaf(q4.x, kb.x, c2); c2 = fmaf(q4.y, kb.y, c2);              \
            c2 = fmaf(q4.z, kb.z, c2); c2 = fmaf(q4.w, kb.w, c2);              \
            acc[2][2 * (TT) + 1] = c2;                                         \
            q4 = *(const float4*)&qb3[s << 2];                                 \
            a = acc[3][2 * (TT)];                                              \
            a = fmaf(q4.x, ka.x, a); a = fmaf(q4.y, ka.y, a);                  \
            a = fmaf(q4.z, ka.z, a); a = fmaf(q4.w, ka.w, a);                  \
            acc[3][2 * (TT)] = a;                                              \
            c2 = acc[3][2 * (TT) + 1];                                         \
            c2 = fmaf(q4.x, kb.x, c2); c2 = fmaf(q4.y, kb.y, c2);              \
            c2 = fmaf(q4.z, kb.z, c2); c2 = fmaf(q4.w, kb.w, c2);              \
            acc[3][2 * (TT) + 1] = c2;                                         \
        }                                                                      \
        if ((TT) < 15) {                                                       \
            stage_write(1 - ((TT) & 1));                                       \
            if ((TT) < 14) stage_load((TT) + 2);                               \
            __syncthreads();                                                   \
        }                                                                      \
    }

    STEP(0)  STEP(1)  STEP(2)  STEP(3)
    STEP(4)  STEP(5)  STEP(6)  STEP(7)
    STEP(8)  STEP(9)  STEP(10) STEP(11)
    STEP(12) STEP(13) STEP(14) STEP(15)
#undef STEP

    // phase B: per wave, 4 rows; exact 64th-largest via bit bisection on acc
#pragma unroll 1
    for (int rq = 0; rq < 4; ++rq) {
        float    fv[32];
        unsigned uv[32];
#pragma unroll
        for (int m = 0; m < 32; ++m) {
            const float x = acc[rq][m] * 0.125f;
            fv[m] = x;
            const unsigned bx = __float_as_uint(x);
            uv[m] = bx ^ (unsigned)(((int)bx >> 31) | 0x80000000);
        }
        unsigned lo = 0;
#pragma unroll 1
        for (int bit = 31; bit >= 0; --bit) {
            const unsigned mid = lo | (1u << bit);
            int c = 0;
#pragma unroll
            for (int m = 0; m < 32; ++m) {
                unsigned long long ball = __ballot(uv[m] >= mid);
                c += __popcll(ball);
            }
            if (c >= 64) lo = mid;   // uniform (ballot count is wave-uniform)
        }
        unsigned um = 0;
#pragma unroll
        for (int m = 0; m < 32; ++m) um = uv[m] > um ? uv[m] : um;
#pragma unroll
        for (int off = 1; off < 64; off <<= 1) {
            const unsigned o = (unsigned)__shfl_xor((int)um, off, 64);
            um = o > um ? o : um;
        }
        const unsigned mb = (um & 0x80000000u) ? (um ^ 0x80000000u) : ~um;
        const float Mx = __uint_as_float(mb);

        float zs = 0.f;
#pragma unroll
        for (int m = 0; m < 32; ++m) {
            const bool keep = uv[m] >= lo;
            const float ex = keep ? __expf(fv[m] - Mx) : 0.f;
            fv[m] = ex;
            zs += ex;
        }
#pragma unroll
        for (int off = 1; off < 64; off <<= 1) zs += __shfl_xor(zs, off, 64);
        const float zinv = 1.0f / zs;

        const size_t grow = (size_t)bh * 2048 + wr0 + rq;
        float* vd          = svals + grow * SLOTS;
        unsigned short* id = sidx  + grow * SLOTS;
        const unsigned long long pre64 = (1ull << lane) - 1ull;
        int base = 0;
#pragma unroll 1
        for (int m = 0; m < 32; ++m) {
            const bool keep = uv[m] >= lo;
            unsigned long long ball = __ballot(keep);
            if (keep) {
                const int my = base + __popcll(ball & pre64);
                if (my < SLOTS) {
                    vd[my] = fv[m] * zinv;
                    id[my] = (unsigned short)(((m >> 1) << 7) + ((m & 1) << 6) + lane);
                }
            }
            base += __popcll(ball);
        }
        if (lane == 0) scnt[grow] = base < SLOTS ? base : SLOTS;
    }
}

// ---------------------------------------------------------------------------
// K3: sparse attn application (unchanged).
// ---------------------------------------------------------------------------
__global__ __launch_bounds__(256)
void spmm(const float* __restrict__ svals, const unsigned short* __restrict__ sidx,
          const int* __restrict__ scnt, const float* __restrict__ qkv,
          const float* __restrict__ vin, float* __restrict__ vout,
          float* __restrict__ res, const float* __restrict__ alphas_raw, int order)
{
    const int lane = threadIdx.x & 63;
    const int gr   = (blockIdx.x << 2) + (threadIdx.x >> 6);  // 0..65535
    const int bh   = gr >> 11, n = gr & 2047;
    const int b    = bh >> 3,  h = bh & 7;

    const float* vb;
    int stride;
    if (order == 0) { vb = qkv + (size_t)b * 2048 * 1536 + 1024 + (h << 6); stride = 1536; }
    else            { vb = vin + ((size_t)bh << 17);                        stride = 64;   }

    const int cnt = scnt[gr];
    const float* va          = svals + (size_t)gr * SLOTS;
    const unsigned short* ia = sidx  + (size_t)gr * SLOTS;

    float acc = 0.f;
    int j = 0;
    for (; j + 4 <= cnt; j += 4) {
        float a0 = va[j], a1 = va[j + 1], a2 = va[j + 2], a3 = va[j + 3];
        int   i0 = ia[j], i1 = ia[j + 1], i2 = ia[j + 2], i3 = ia[j + 3];
        acc += a0 * vb[(size_t)i0 * stride + lane];
        acc += a1 * vb[(size_t)i1 * stride + lane];
        acc += a2 * vb[(size_t)i2 * stride + lane];
        acc += a3 * vb[(size_t)i3 * stride + lane];
    }
    for (; j < cnt; ++j) acc += va[j] * vb[(size_t)ia[j] * stride + lane];

    if (order < 2) vout[((size_t)gr << 6) + lane] = acc;

    float ar    = alphas_raw[(order << 3) + h];
    float alpha = ar * 0.5f * (1.0f + erff(ar * 0.70710678f));  // exact gelu
    size_t ro = ((size_t)b * 2048 + n) * 512 + (h << 6) + lane;
    float av  = alpha * acc;
    if (order == 0) res[ro] = av;
    else            res[ro] += av;
}

// ---------------------------------------------------------------------------
extern "C" void kernel_launch(void* const* d_in, const int* in_sizes, int n_in,
                              void* d_out, int out_size, void* d_ws, size_t ws_size,
                              hipStream_t stream)
{
    const float* x      = (const float*)d_in[0];
    const float* Wqkv   = (const float*)d_in[1];
    const float* bqkv   = (const float*)d_in[2];
    const float* Wout   = (const float*)d_in[3];
    const float* bout   = (const float*)d_in[4];
    const float* alphas = (const float*)d_in[5];
    float* out = (float*)d_out;

    // workspace layout (bytes)
    char* ws = (char*)d_ws;
    float*          qkvb  = (float*)ws;                       // 8192*1536*4 = 50331648
    float*          svals = (float*)(ws + 50331648);          // 65536*80*4  = 20971520
    unsigned short* sidxp = (unsigned short*)(ws + 71303168); // 65536*80*2  = 10485760
    int*            scntp = (int*)(ws + 81788928);            // 65536*4     = 262144
    float*          v1    = (float*)(ws + 82051072);          // 16777216
    float*          v2    = (float*)(ws + 98828288);          // 16777216
    float*          resb  = (float*)(ws + 115605504);         // 16777216
    if (ws_size < 132382720) return;                          // need ~126 MB

    // K1: qkv = x @ Wqkv + bqkv
    sgemm_bias<<<dim3(1536 / 128, 8192 / 128), 256, 0, stream>>>(
        x, Wqkv, bqkv, qkvb, 8192, 1536, 512);

    // K2: scores (in regs) -> exact top-64(+ties) -> softmax -> sparse rows
    scores_topk<<<dim3(128, 32), 256, 0, stream>>>(qkvb, svals, sidxp, scntp);

    // K3 x3: polynomial filter (sparse A applications)
    spmm<<<16384, 256, 0, stream>>>(svals, sidxp, scntp, qkvb, nullptr, v1, resb, alphas, 0);
    spmm<<<16384, 256, 0, stream>>>(svals, sidxp, scntp, qkvb, v1, v2, resb, alphas, 1);
    spmm<<<16384, 256, 0, stream>>>(svals, sidxp, scntp, qkvb, v2, nullptr, resb, alphas, 2);

    // K4: out = res @ Wout + bout
    sgemm_bias<<<dim3(512 / 128, 8192 / 128), 256, 0, stream>>>(
        resb, Wout, bout, out, 8192, 512, 512);
}

// Round 5
// 3122.072 us; speedup vs baseline: 1.2046x; 1.1011x over previous
//
#include <hip/hip_runtime.h>
#include <hip/hip_bf16.h>

// Problem constants: B=4, N=2048, DIM=512, H=8, DH=64, ORDER=3, TOPK=64, INNER=512
#define SLOTS 80   // sparse slots per row (64 + tie headroom)

// ---------------------------------------------------------------------------
// K1/K4: fp32 tiled GEMM with bias: C = A(MxK) @ B(KxN) + bias(N)
// BM=BN=128, BK=16, 256 threads, 8x8 per thread. (unchanged)
// ---------------------------------------------------------------------------
__global__ __launch_bounds__(256)
void sgemm_bias(const float* __restrict__ A, const float* __restrict__ Bm,
                const float* __restrict__ bias, float* __restrict__ C,
                int M, int N, int K)
{
    __shared__ float As[16][132];
    __shared__ float Bs[16][132];

    const int t  = threadIdx.x;
    const int tx = t & 15, ty = t >> 4;
    const int bm = blockIdx.y << 7, bn = blockIdx.x << 7;

    const int arow = t >> 2,  ak4 = (t & 3) << 2;
    const int bkr  = t >> 5,  bc4 = (t & 31) << 2;

    float4 pa[2], pb[2];
#pragma unroll
    for (int s = 0; s < 2; ++s) {
        pa[s] = *(const float4*)&A[(size_t)(bm + arow + (s << 6)) * K + ak4];
        pb[s] = *(const float4*)&Bm[(size_t)(bkr + (s << 3)) * N + bn + bc4];
    }

    float acc[8][8] = {};

    for (int k0 = 0; k0 < K; k0 += 16) {
        __syncthreads();
#pragma unroll
        for (int s = 0; s < 2; ++s) {
            const int ar = arow + (s << 6);
            As[ak4 + 0][ar] = pa[s].x;
            As[ak4 + 1][ar] = pa[s].y;
            As[ak4 + 2][ar] = pa[s].z;
            As[ak4 + 3][ar] = pa[s].w;
            *(float4*)&Bs[bkr + (s << 3)][bc4] = pb[s];
        }
        __syncthreads();
        if (k0 + 16 < K) {
#pragma unroll
            for (int s = 0; s < 2; ++s) {
                pa[s] = *(const float4*)&A[(size_t)(bm + arow + (s << 6)) * K + k0 + 16 + ak4];
                pb[s] = *(const float4*)&Bm[(size_t)(k0 + 16 + bkr + (s << 3)) * N + bn + bc4];
            }
        }
#pragma unroll
        for (int kk = 0; kk < 16; ++kk) {
            float4 a0 = *(const float4*)&As[kk][(ty << 3) + 0];
            float4 a1 = *(const float4*)&As[kk][(ty << 3) + 4];
            float4 b0 = *(const float4*)&Bs[kk][(tx << 2)];
            float4 b1 = *(const float4*)&Bs[kk][64 + (tx << 2)];
            float ar[8] = {a0.x, a0.y, a0.z, a0.w, a1.x, a1.y, a1.z, a1.w};
            float br[8] = {b0.x, b0.y, b0.z, b0.w, b1.x, b1.y, b1.z, b1.w};
#pragma unroll
            for (int i = 0; i < 8; ++i)
#pragma unroll
                for (int j = 0; j < 8; ++j)
                    acc[i][j] = fmaf(ar[i], br[j], acc[i][j]);
        }
    }

    float bb[8];
#pragma unroll
    for (int j = 0; j < 4; ++j) {
        bb[j]     = bias[bn + (tx << 2) + j];
        bb[j + 4] = bias[bn + 64 + (tx << 2) + j];
    }
#pragma unroll
    for (int i = 0; i < 8; ++i) {
        const size_t row = (size_t)(bm + (ty << 3) + i);
        float4 o0 = {acc[i][0] + bb[0], acc[i][1] + bb[1], acc[i][2] + bb[2], acc[i][3] + bb[3]};
        float4 o1 = {acc[i][4] + bb[4], acc[i][5] + bb[5], acc[i][6] + bb[6], acc[i][7] + bb[7]};
        *(float4*)&C[row * N + bn + (tx << 2)]      = o0;
        *(float4*)&C[row * N + bn + 64 + (tx << 2)] = o1;
    }
}

// ---------------------------------------------------------------------------
// K2 v5: row-stationary scores + fused exact top-k. ALL register-array
// indices are compile-time literals (compute loop macro STEP, phase B macro
// PHASEB, compaction fully unrolled) -> no scratch (rule #20).
// Block = 4 waves; wave owns 4 rows; lane owns 32 cols (acc[4][32] VGPR).
// K streamed via double-buffered swizzled LDS tiles (128 cols x 64 d).
// Per-score fmaf chain d-ascending 0..63 -> bit-identical to R2/R3/R4.
// ---------------------------------------------------------------------------
__global__ __launch_bounds__(256, 2)
void scores_topk(const float* __restrict__ qkv, float* __restrict__ svals,
                 unsigned short* __restrict__ sidx, int* __restrict__ scnt)
{
    __shared__ float kt[16384];   // 2 x (128 cols x 64 d), 16B-slot swizzled

    const int t    = threadIdx.x;
    const int lane = t & 63;
    const int wid  = t >> 6;
    const int bh   = blockIdx.y;
    const int b    = bh >> 3, h = bh & 7;
    const size_t rowbase = (size_t)b * 2048;
    const int qoff = h << 6;
    const int koff = 512 + (h << 6);
    const int swz  = lane & 7;

    int wr0 = (blockIdx.x << 4) + (wid << 2);
    wr0 = __builtin_amdgcn_readfirstlane(wr0);
    const float* qb0 = qkv + (rowbase + (size_t)(wr0 + 0)) * 1536 + qoff;
    const float* qb1 = qkv + (rowbase + (size_t)(wr0 + 1)) * 1536 + qoff;
    const float* qb2 = qkv + (rowbase + (size_t)(wr0 + 2)) * 1536 + qoff;
    const float* qb3 = qkv + (rowbase + (size_t)(wr0 + 3)) * 1536 + qoff;

    const int sl = t & 15;
    float4 pre[8];

    auto stage_load = [&](int tn) {
#pragma unroll
        for (int i = 0; i < 8; ++i) {
            const int c = (t >> 4) + (i << 4);
            pre[i] = *(const float4*)
                &qkv[(rowbase + (size_t)((tn << 7) + c)) * 1536 + koff + (sl << 2)];
        }
    };
    auto stage_write = [&](int bufi) {
#pragma unroll
        for (int i = 0; i < 8; ++i) {
            const int c = (t >> 4) + (i << 4);
            *(float4*)&kt[(bufi << 13) + (c << 6) + ((sl ^ (c & 7)) << 2)] = pre[i];
        }
    };

    stage_load(0);
    stage_write(0);
    stage_load(1);
    __syncthreads();         // buf0 ready

    float acc[4][32];
#pragma unroll
    for (int r = 0; r < 4; ++r)
#pragma unroll
        for (int m = 0; m < 32; ++m) acc[r][m] = 0.f;

#define ROWFMA(RQ, QB, TT)                                                     \
    {                                                                          \
        const float4 q4 = *(const float4*)&QB[s << 2];                         \
        float a = acc[RQ][2 * (TT)];                                           \
        a = fmaf(q4.x, ka.x, a); a = fmaf(q4.y, ka.y, a);                      \
        a = fmaf(q4.z, ka.z, a); a = fmaf(q4.w, ka.w, a);                      \
        acc[RQ][2 * (TT)] = a;                                                 \
        float c2 = acc[RQ][2 * (TT) + 1];                                      \
        c2 = fmaf(q4.x, kb.x, c2); c2 = fmaf(q4.y, kb.y, c2);                  \
        c2 = fmaf(q4.z, kb.z, c2); c2 = fmaf(q4.w, kb.w, c2);                  \
        acc[RQ][2 * (TT) + 1] = c2;                                            \
    }

#define STEP(TT)                                                               \
    {                                                                          \
        const int cb = ((TT) & 1) << 13;                                       \
        _Pragma("unroll")                                                      \
        for (int s = 0; s < 16; ++s) {                                         \
            const float4 ka = *(const float4*)&kt[cb + (lane << 6) + ((s ^ swz) << 2)];        \
            const float4 kb = *(const float4*)&kt[cb + 4096 + (lane << 6) + ((s ^ swz) << 2)]; \
            ROWFMA(0, qb0, TT) ROWFMA(1, qb1, TT)                              \
            ROWFMA(2, qb2, TT) ROWFMA(3, qb3, TT)                              \
        }                                                                      \
        if ((TT) < 15) {                                                       \
            stage_write(1 - ((TT) & 1));                                       \
            if ((TT) < 14) stage_load((TT) + 2);                               \
            __syncthreads();                                                   \
        }                                                                      \
    }

    STEP(0)  STEP(1)  STEP(2)  STEP(3)
    STEP(4)  STEP(5)  STEP(6)  STEP(7)
    STEP(8)  STEP(9)  STEP(10) STEP(11)
    STEP(12) STEP(13) STEP(14) STEP(15)
#undef STEP
#undef ROWFMA

    // phase B per row, all indices literal. Scaled score and exp-value are
    // stored back into acc[RQ][m]; uv[32] is the only extra array.
    const unsigned long long pre64 = (1ull << lane) - 1ull;

#define PHASEB(RQ)                                                             \
    {                                                                          \
        unsigned uv[32];                                                       \
        _Pragma("unroll")                                                      \
        for (int m = 0; m < 32; ++m) {                                         \
            const float x = acc[RQ][m] * 0.125f;                               \
            acc[RQ][m] = x;                                                    \
            const unsigned bx = __float_as_uint(x);                            \
            uv[m] = bx ^ (unsigned)(((int)bx >> 31) | 0x80000000);             \
        }                                                                      \
        unsigned lo = 0;                                                       \
        _Pragma("unroll 1")                                                    \
        for (int bit = 31; bit >= 0; --bit) {                                  \
            const unsigned mid = lo | (1u << bit);                             \
            int c = 0;                                                         \
            _Pragma("unroll")                                                  \
            for (int m = 0; m < 32; ++m)                                       \
                c += __popcll(__ballot(uv[m] >= mid));                         \
            if (c >= 64) lo = mid;                                             \
        }                                                                      \
        unsigned um = 0;                                                       \
        _Pragma("unroll")                                                      \
        for (int m = 0; m < 32; ++m) um = uv[m] > um ? uv[m] : um;             \
        _Pragma("unroll")                                                      \
        for (int off = 1; off < 64; off <<= 1) {                               \
            const unsigned o = (unsigned)__shfl_xor((int)um, off, 64);         \
            um = o > um ? o : um;                                              \
        }                                                                      \
        const unsigned mb = (um & 0x80000000u) ? (um ^ 0x80000000u) : ~um;     \
        const float Mx = __uint_as_float(mb);                                  \
        float zs = 0.f;                                                        \
        _Pragma("unroll")                                                      \
        for (int m = 0; m < 32; ++m) {                                         \
            const bool keep = uv[m] >= lo;                                     \
            const float ex = keep ? __expf(acc[RQ][m] - Mx) : 0.f;             \
            acc[RQ][m] = ex;                                                   \
            zs += ex;                                                          \
        }                                                                      \
        _Pragma("unroll")                                                      \
        for (int off = 1; off < 64; off <<= 1) zs += __shfl_xor(zs, off, 64);  \
        const float zinv = 1.0f / zs;                                          \
        const size_t grow = (size_t)bh * 2048 + wr0 + (RQ);                    \
        float* vd          = svals + grow * SLOTS;                             \
        unsigned short* id = sidx  + grow * SLOTS;                             \
        int base = 0;                                                          \
        _Pragma("unroll")                                                      \
        for (int m = 0; m < 32; ++m) {                                         \
            const bool keep = uv[m] >= lo;                                     \
            unsigned long long ball = __ballot(keep);                          \
            if (keep) {                                                        \
                const int my = base + __popcll(ball & pre64);                  \
                if (my < SLOTS) {                                              \
                    vd[my] = acc[RQ][m] * zinv;                                \
                    id[my] = (unsigned short)(((m >> 1) << 7) + ((m & 1) << 6) + lane); \
                }                                                              \
            }                                                                  \
            base += __popcll(ball);                                            \
        }                                                                      \
        if (lane == 0) scnt[grow] = base < SLOTS ? base : SLOTS;               \
    }

    PHASEB(0)
    PHASEB(1)
    PHASEB(2)
    PHASEB(3)
#undef PHASEB
}

// ---------------------------------------------------------------------------
// K3: sparse attn application (unchanged).
// ---------------------------------------------------------------------------
__global__ __launch_bounds__(256)
void spmm(const float* __restrict__ svals, const unsigned short* __restrict__ sidx,
          const int* __restrict__ scnt, const float* __restrict__ qkv,
          const float* __restrict__ vin, float* __restrict__ vout,
          float* __restrict__ res, const float* __restrict__ alphas_raw, int order)
{
    const int lane = threadIdx.x & 63;
    const int gr   = (blockIdx.x << 2) + (threadIdx.x >> 6);  // 0..65535
    const int bh   = gr >> 11, n = gr & 2047;
    const int b    = bh >> 3,  h = bh & 7;

    const float* vb;
    int stride;
    if (order == 0) { vb = qkv + (size_t)b * 2048 * 1536 + 1024 + (h << 6); stride = 1536; }
    else            { vb = vin + ((size_t)bh << 17);                        stride = 64;   }

    const int cnt = scnt[gr];
    const float* va          = svals + (size_t)gr * SLOTS;
    const unsigned short* ia = sidx  + (size_t)gr * SLOTS;

    float acc = 0.f;
    int j = 0;
    for (; j + 4 <= cnt; j += 4) {
        float a0 = va[j], a1 = va[j + 1], a2 = va[j + 2], a3 = va[j + 3];
        int   i0 = ia[j], i1 = ia[j + 1], i2 = ia[j + 2], i3 = ia[j + 3];
        acc += a0 * vb[(size_t)i0 * stride + lane];
        acc += a1 * vb[(size_t)i1 * stride + lane];
        acc += a2 * vb[(size_t)i2 * stride + lane];
        acc += a3 * vb[(size_t)i3 * stride + lane];
    }
    for (; j < cnt; ++j) acc += va[j] * vb[(size_t)ia[j] * stride + lane];

    if (order < 2) vout[((size_t)gr << 6) + lane] = acc;

    float ar    = alphas_raw[(order << 3) + h];
    float alpha = ar * 0.5f * (1.0f + erff(ar * 0.70710678f));  // exact gelu
    size_t ro = ((size_t)b * 2048 + n) * 512 + (h << 6) + lane;
    float av  = alpha * acc;
    if (order == 0) res[ro] = av;
    else            res[ro] += av;
}

// ---------------------------------------------------------------------------
extern "C" void kernel_launch(void* const* d_in, const int* in_sizes, int n_in,
                              void* d_out, int out_size, void* d_ws, size_t ws_size,
                              hipStream_t stream)
{
    const float* x      = (const float*)d_in[0];
    const float* Wqkv   = (const float*)d_in[1];
    const float* bqkv   = (const float*)d_in[2];
    const float* Wout   = (const float*)d_in[3];
    const float* bout   = (const float*)d_in[4];
    const float* alphas = (const float*)d_in[5];
    float* out = (float*)d_out;

    // workspace layout (bytes)
    char* ws = (char*)d_ws;
    float*          qkvb  = (float*)ws;                       // 8192*1536*4 = 50331648
    float*          svals = (float*)(ws + 50331648);          // 65536*80*4  = 20971520
    unsigned short* sidxp = (unsigned short*)(ws + 71303168); // 65536*80*2  = 10485760
    int*            scntp = (int*)(ws + 81788928);            // 65536*4     = 262144
    float*          v1    = (float*)(ws + 82051072);          // 16777216
    float*          v2    = (float*)(ws + 98828288);          // 16777216
    float*          resb  = (float*)(ws + 115605504);         // 16777216
    if (ws_size < 132382720) return;                          // need ~126 MB

    // K1: qkv = x @ Wqkv + bqkv
    sgemm_bias<<<dim3(1536 / 128, 8192 / 128), 256, 0, stream>>>(
        x, Wqkv, bqkv, qkvb, 8192, 1536, 512);

    // K2: scores (in regs) -> exact top-64(+ties) -> softmax -> sparse rows
    scores_topk<<<dim3(128, 32), 256, 0, stream>>>(qkvb, svals, sidxp, scntp);

    // K3 x3: polynomial filter (sparse A applications)
    spmm<<<16384, 256, 0, stream>>>(svals, sidxp, scntp, qkvb, nullptr, v1, resb, alphas, 0);
    spmm<<<16384, 256, 0, stream>>>(svals, sidxp, scntp, qkvb, v1, v2, resb, alphas, 1);
    spmm<<<16384, 256, 0, stream>>>(svals, sidxp, scntp, qkvb, v2, nullptr, resb, alphas, 2);

    // K4: out = res @ Wout + bout
    sgemm_bias<<<dim3(512 / 128, 8192 / 128), 256, 0, stream>>>(
        resb, Wout, bout, out, 8192, 512, 512);
}